// Round 2
// baseline (552.543 us; speedup 1.0000x reference)
//
#include <hip/hip_runtime.h>

// CausalNet CC-loss, closed-form reformulation.
// B=32, T=256, b=16 hardcoded per problem instance.
//
// Math (verified against reference semantics):
//   stop_rev[...,e] = stop_orig[...,1-e]
//   A[i][b]  = action[i-1][b] (i=1..T);  SPe0/e1[i][b] = stop_orig[i][b][0/1]
//   ST[τ][b] = start[τ][b] - 0.5
//   PA(t)=Σ_{i<=t}A, QS(t)=Σ_{i<=t}SPe1
//   f_t[b,τ,1] = U[b,τ] + V[b,t]   (live τ < t; dead entries exp to exact 0)
//     U[b,τ] = G(τ) + ST[τ][b] - PA(τ)[b] - QS(τ)[b]      (G(0)=0)
//     V[b,t] = PA(t)[b] + QS(t-1)[b] + SPe0[t][b]
//     G(t)   = lse_b( V[b,t] + lse_{τ<t} U[b,τ] )   [= seg at step t+1]
//   total_logp = G(L).  Backward e=1 channel is b-independent scalar W[t].
//   total_cc = Σ_{t<=L} Σ_{τ<t,b} exp(U+V+W[t]-G(L)) * pens[β,τ,t,b]
constexpr int B  = 32;
constexpr int T  = 256;
constexpr int NB = 16;
#define NEGV (-1000000000.0f)
#define AP   0.5f

__device__ __forceinline__ void ldrow16(const float* p, float (&o)[16]) {
    const float4* q = (const float4*)p;
    float4 x0 = q[0], x1 = q[1], x2 = q[2], x3 = q[3];
    o[0]=x0.x; o[1]=x0.y; o[2]=x0.z; o[3]=x0.w;
    o[4]=x1.x; o[5]=x1.y; o[6]=x1.z; o[7]=x1.w;
    o[8]=x2.x; o[9]=x2.y; o[10]=x2.z; o[11]=x2.w;
    o[12]=x3.x; o[13]=x3.y; o[14]=x3.z; o[15]=x3.w;
}

// stp LDS row: 32 floats laid out [b][e] (orig e order). e0 -> SPe0, e1 -> SPe1.
__device__ __forceinline__ void ldstp(const float* p, float (&e0)[16], float (&e1)[16]) {
    const float4* q = (const float4*)p;
#pragma unroll
    for (int k = 0; k < 8; ++k) {
        float4 x = q[k];
        e0[2*k]   = x.x; e1[2*k]   = x.y;
        e0[2*k+1] = x.z; e1[2*k+1] = x.w;
    }
}

__device__ __forceinline__ float tmax16(const float (&y)[16]) {
    float w[8];
#pragma unroll
    for (int j = 0; j < 8; ++j) w[j] = fmaxf(y[j], y[j+8]);
#pragma unroll
    for (int j = 0; j < 4; ++j) w[j] = fmaxf(w[j], w[j+4]);
    w[0] = fmaxf(w[0], w[2]); w[1] = fmaxf(w[1], w[3]);
    return fmaxf(w[0], w[1]);
}

__device__ __forceinline__ float tsumexp16(const float (&y)[16], float m) {
    float w[8];
#pragma unroll
    for (int j = 0; j < 8; ++j) w[j] = __expf(y[j]-m) + __expf(y[j+8]-m);
#pragma unroll
    for (int j = 0; j < 4; ++j) w[j] += w[j+4];
    w[0] += w[2]; w[1] += w[3];
    return w[0] + w[1];
}

#define ST16(ptr, arr) do { float4* p_ = (float4*)(ptr); \
    p_[0] = make_float4((arr)[0],(arr)[1],(arr)[2],(arr)[3]); \
    p_[1] = make_float4((arr)[4],(arr)[5],(arr)[6],(arr)[7]); \
    p_[2] = make_float4((arr)[8],(arr)[9],(arr)[10],(arr)[11]); \
    p_[3] = make_float4((arr)[12],(arr)[13],(arr)[14],(arr)[15]); } while(0)

// One block per batch. Stage inputs to LDS (exactly 64KB), then:
//   wave 0: forward scan  -> Ubuf, Vbuf, TLbuf, out[0]
//   wave 1: backward scan -> Wbuf
// All 16 b-values live in registers in EVERY lane (redundant compute,
// zero cross-lane traffic in the dependency chain). Depth-1 LDS prefetch.
__global__ __launch_bounds__(256, 1) void scan_kernel(
    const float* __restrict__ act_g,   // [B][T][16]
    const float* __restrict__ stp_g,   // [B][T+1][16][2] (original e order)
    const float* __restrict__ str_g,   // [B][T+1][16]
    const int*   __restrict__ len_g,   // [B]
    float* __restrict__ Wbuf,          // [B][T+1]
    float* __restrict__ TLbuf,         // [B]
    float* __restrict__ Ubuf,          // [B][T][16]
    float* __restrict__ Vbuf,          // [B][T+1][16]
    float* __restrict__ out)           // out[0] += total_logp
{
    __shared__ float sm[16384];                 // 64 KB exactly
    float* act  = sm;                           // [256][16]  rows 0..T-1
    float* stp  = sm + 4096;                    // [256][32]  global rows 1..T
    float* strt = sm + 4096 + 8192;             // [256][16]  rows 0..T-1

    const int beta = blockIdx.x;
    const int tid  = threadIdx.x;

    // ---- stage (coalesced float4) ----
    {
        const float4* a4 = (const float4*)(act_g + (size_t)beta * (T * NB));
        const float4* s4 = (const float4*)(stp_g + (size_t)beta * ((T + 1) * NB * 2) + 32); // skip row 0
        const float4* t4 = (const float4*)(str_g + (size_t)beta * ((T + 1) * NB));
        float4* actv = (float4*)act;
        float4* stpv = (float4*)stp;
        float4* strv = (float4*)strt;
        for (int i = tid; i < 1024; i += 256) actv[i] = a4[i];
        for (int i = tid; i < 2048; i += 256) stpv[i] = s4[i];
        for (int i = tid; i < 1024; i += 256) strv[i] = t4[i];
    }
    __syncthreads();

    const int wid  = tid >> 6;
    const int lane = tid & 63;
    const int L    = len_g[beta];

    if (wid == 0) {
        // ---------------- forward ----------------
        float PA[16], Q[16], R[16];
        float TL = 0.f;
#pragma unroll
        for (int j = 0; j < 16; ++j) { PA[j] = 0.f; Q[j] = 0.f; R[j] = strt[j] - AP; }
        if (lane == 0) ST16(Ubuf + (size_t)beta * (T * NB), R);   // U row 0

        float ca[16], ce0[16], ce1[16], cst[16];
        ldrow16(act, ca);                 // act row 0 (for t=1)
        ldstp  (stp, ce0, ce1);           // stp LDS row 0 = global row 1
        ldrow16(strt + 16, cst);          // strt row 1 (used if t<T)

        for (int t = 1; t <= T; ++t) {
            // prefetch next iteration's rows (clamped; t=T values unused)
            float na[16], ne0[16], ne1[16], nst[16];
            ldrow16(act + (t & 255) * 16, na);
            ldstp  (stp + (t & 255) * 32, ne0, ne1);
            ldrow16(strt + ((t + 1) & 255) * 16, nst);

            float V[16], y[16];
#pragma unroll
            for (int j = 0; j < 16; ++j) {
                PA[j] += ca[j];
                V[j] = PA[j] + Q[j] + ce0[j];
                y[j] = R[j] + V[j];
            }
            float m = tmax16(y);
            float G = m + __logf(tsumexp16(y, m));
            if (t == L) TL = G;
#pragma unroll
            for (int j = 0; j < 16; ++j) Q[j] += ce1[j];

            float U[16];
            if (t < T) {
#pragma unroll
                for (int j = 0; j < 16; ++j) {
                    U[j] = G + (cst[j] - AP) - PA[j] - Q[j];
                    float mm = fmaxf(R[j], U[j]);
                    R[j] = mm + __logf(__expf(R[j] - mm) + __expf(U[j] - mm));
                }
            }
            if (lane == 0) {
                ST16(Vbuf + (size_t)beta * ((T + 1) * NB) + t * 16, V);
                if (t < T) ST16(Ubuf + (size_t)beta * (T * NB) + t * 16, U);
            }
#pragma unroll
            for (int j = 0; j < 16; ++j) { ca[j]=na[j]; ce0[j]=ne0[j]; ce1[j]=ne1[j]; cst[j]=nst[j]; }
        }
        if (lane == 0) {
            TLbuf[beta] = TL;
            atomicAdd(out, TL);
        }
    } else if (wid == 1) {
        // ---------------- backward ----------------
        float fn0[16], fn1 = 0.f;
#pragma unroll
        for (int j = 0; j < 16; ++j) fn0[j] = NEGV;
        if (lane == 0) Wbuf[beta * (T + 1) + T] = 0.f;

        float ca[16], ce0[16], ce1[16], cst[16];
        ldrow16(act + (T - 1) * 16, ca);
        ldstp  (stp + (T - 1) * 32, ce0, ce1);   // LDS row i = global row i+1
        ldrow16(strt + (T - 1) * 16, cst);

        for (int i = T - 1; i >= 0; --i) {
            float na[16], ne0[16], ne1[16], nst[16];
            const int pr = (i - 1) & 255;        // i=0 -> 255, unused
            ldrow16(act + pr * 16, na);
            ldstp  (stp + pr * 32, ne0, ne1);
            ldrow16(strt + pr * 16, nst);

            float y[16], f0c[16];
#pragma unroll
            for (int j = 0; j < 16; ++j) {
                float t0 = ce1[j] + fn0[j];      // rev e0 = orig e1, pairs f_next[...,0]
                float t1 = ce0[j] + fn1;         // rev e1 = orig e0, pairs f_next[...,1]
                float mm = fmaxf(t0, t1);
                f0c[j] = ca[j] + mm + __logf(__expf(t0 - mm) + __expf(t1 - mm));
                y[j] = (cst[j] - AP) + f0c[j];
            }
            float m = tmax16(y);
            float f1c = m + __logf(tsumexp16(y, m));
            const bool mk = (i < L);             // masks[beta][i] > 0
#pragma unroll
            for (int j = 0; j < 16; ++j) fn0[j] = mk ? f0c[j] : NEGV;
            fn1 = mk ? f1c : 0.f;
            if (i >= 1 && lane == 0) Wbuf[beta * (T + 1) + i] = fn1;
#pragma unroll
            for (int j = 0; j < 16; ++j) { ca[j]=na[j]; ce0[j]=ne0[j]; ce1[j]=ne1[j]; cst[j]=nst[j]; }
        }
    }
}

// Fully parallel marginal + penalty accumulation over the masked triangle.
__global__ __launch_bounds__(256) void cc_kernel(
    const float* __restrict__ pens,   // [B][257][257][16]
    const int*   __restrict__ len_g,
    const float* __restrict__ Wbuf,
    const float* __restrict__ TLbuf,
    const float* __restrict__ Ubuf,
    const float* __restrict__ Vbuf,
    float* __restrict__ out)
{
    const int beta = blockIdx.x;
    const int tid  = threadIdx.x;
    const int L    = len_g[beta];
    const float tl = TLbuf[beta];
    const float* Ub = Ubuf + (size_t)beta * (T * NB);
    const float* Vb = Vbuf + (size_t)beta * ((T + 1) * NB);
    const float* Pb = pens + (size_t)beta * ((size_t)(T + 1) * (T + 1) * NB);

    float local = 0.f;
    for (int t = blockIdx.y + 1; t <= T; t += gridDim.y) {
        if (t > L) continue;                       // masks[beta][t-1] == 0
        const float base = Wbuf[beta * (T + 1) + t] - tl;
        const int n = t * 16;
        for (int e = tid; e < n; e += 256) {
            const int tau = e >> 4, bb = e & 15;
            float marg = Ub[tau * 16 + bb] + Vb[t * 16 + bb] + base;
            local += __expf(marg) * Pb[(size_t)tau * ((T + 1) * NB) + t * 16 + bb];
        }
    }
    // block reduce
#pragma unroll
    for (int off = 1; off < 64; off <<= 1) local += __shfl_xor(local, off);
    __shared__ float red[4];
    if ((tid & 63) == 0) red[tid >> 6] = local;
    __syncthreads();
    if (tid == 0) atomicAdd(out + 1, red[0] + red[1] + red[2] + red[3]);
}

extern "C" void kernel_launch(void* const* d_in, const int* in_sizes, int n_in,
                              void* d_out, int out_size, void* d_ws, size_t ws_size,
                              hipStream_t stream) {
    (void)in_sizes; (void)n_in; (void)out_size; (void)ws_size;
    const float* act  = (const float*)d_in[0];
    const float* stp  = (const float*)d_in[1];
    const float* strt = (const float*)d_in[2];
    const float* pens = (const float*)d_in[3];
    // d_in[4] = masks (implied by lengths; unused)
    const int*   lens = (const int*)d_in[5];
    float* out = (float*)d_out;

    float* ws    = (float*)d_ws;
    float* Wbuf  = ws;                        // B*(T+1)      = 8224
    float* TLbuf = Wbuf + B * (T + 1);        // B            = 32
    float* Ubuf  = TLbuf + B;                 // B*T*16       = 131072
    float* Vbuf  = Ubuf + (size_t)B * T * NB; // B*(T+1)*16   = 131584

    hipMemsetAsync(d_out, 0, 2 * sizeof(float), stream);
    scan_kernel<<<B, 256, 0, stream>>>(act, stp, strt, lens, Wbuf, TLbuf, Ubuf, Vbuf, out);
    cc_kernel<<<dim3(B, 32), 256, 0, stream>>>(pens, lens, Wbuf, TLbuf, Ubuf, Vbuf, out);
}

// Round 6
// 258.556 us; speedup vs baseline: 2.1370x; 2.1370x over previous
//
#include <hip/hip_runtime.h>

// CausalNet CC-loss, closed-form, log2-space, DPP-parallel scan.
// B=32, T=256, b=16 hardcoded.
//
//   f_t[b,tau,1] = U[b,tau] + V[b,t]  (tau < t)
//   U[b,tau] = G(tau) + ST(tau,b) - PA(tau,b) - QS(tau,b),  G(0)=0
//   V[b,t]   = PA(t,b) + QS(t-1,b) + SPe0(t,b)
//   G(t)     = lse_b( V(b,t) + lse_{tau<t} U(b,tau) ),  total_logp = G(L)
//   backward e=1 channel is the b-independent scalar W[t]
//   total_cc = sum_{t<=L, tau<t, b} exp(U+V+W[t]-G(L)) * pens[beta,tau,t,b]
// All scan state kept in log2 units (inputs pre-scaled by 1/ln2).
constexpr int B  = 32;
constexpr int T  = 256;
constexpr int NB = 16;
#define NEGV   (-1000000000.0f)
#define INVLN2 1.4426950408889634f
#define LN2    0.6931471805599453f
#define AP2    (0.5f * 1.4426950408889634f)   // abstract pen, log2 units

// exp2f: OCML maps to native v_exp_f32 (exp2 IS the hw base — no wrapper cost).
// __log2f: HIP intrinsic -> v_log_f32. (__exp2f does NOT exist in HIP.)
__device__ __forceinline__ float fexp2(float x) { return exp2f(x); }
__device__ __forceinline__ float flog2(float x) { return __log2f(x); }

template<int C>
__device__ __forceinline__ float dppmv(float x) {
    return __int_as_float(__builtin_amdgcn_update_dpp(
        0, __float_as_int(x), C, 0xF, 0xF, true));
}

// Full 16-lane-group butterfly: xor1 (quad_perm 1,0,3,2 = 0xB1), xor2
// (quad_perm 2,3,0,1 = 0x4E), xor7 (row_half_mirror = 0x141), xor15
// (row_mirror = 0x140). All VALU-pipe (v_mov_b32 dpp), no LDS traffic.
__device__ __forceinline__ float lse16_2(float y) {
    float m = y;
    m = fmaxf(m, dppmv<0xB1>(m));
    m = fmaxf(m, dppmv<0x4E>(m));
    m = fmaxf(m, dppmv<0x141>(m));
    m = fmaxf(m, dppmv<0x140>(m));
    float s = fexp2(y - m);
    s += dppmv<0xB1>(s);
    s += dppmv<0x4E>(s);
    s += dppmv<0x141>(s);
    s += dppmv<0x140>(s);
    return m + flog2(s);
}

__device__ __forceinline__ float lse2_2(float a, float b) {
    float m = fmaxf(a, b);
    return m + flog2(fexp2(a - m) + fexp2(b - m));
}

// One block per batch. Stage (log2-scaled) inputs to 64KB LDS, then
// wave 0 runs the forward scan, wave 1 the backward scan. Lane owns b=lane&15
// (lane groups 1-3 of each wave compute identical copies; group 0 stores).
__global__ __launch_bounds__(256) void scan_kernel(
    const float* __restrict__ act_g,   // [B][T][16]
    const float* __restrict__ stp_g,   // [B][T+1][16][2] (orig e order)
    const float* __restrict__ str_g,   // [B][T+1][16]
    const int*   __restrict__ len_g,   // [B]
    float* __restrict__ Wbuf,          // [B][T+1]   log2 units
    float* __restrict__ TLbuf,         // [B]        log2 units
    float* __restrict__ Ubuf,          // [B][T][16] log2 units
    float* __restrict__ Vbuf)          // [B][T+1][16] log2 units
{
    __shared__ float sm[16384];                 // 64 KB
    float* act  = sm;                           // [256][16] rows 0..T-1
    float* stp  = sm + 4096;                    // [256][32] global rows 1..T
    float* strt = sm + 4096 + 8192;             // [256][16] rows 0..T-1

    const int beta = blockIdx.x;
    const int tid  = threadIdx.x;

    { // stage with 1/ln2 scaling
        const float4* a4 = (const float4*)(act_g + (size_t)beta * (T * NB));
        const float4* s4 = (const float4*)(stp_g + (size_t)beta * ((T + 1) * NB * 2) + 32);
        const float4* t4 = (const float4*)(str_g + (size_t)beta * ((T + 1) * NB));
        float4* actv = (float4*)act;
        float4* stpv = (float4*)stp;
        float4* strv = (float4*)strt;
        for (int i = tid; i < 1024; i += 256) {
            float4 v = a4[i];
            actv[i] = make_float4(v.x*INVLN2, v.y*INVLN2, v.z*INVLN2, v.w*INVLN2);
        }
        for (int i = tid; i < 2048; i += 256) {
            float4 v = s4[i];
            stpv[i] = make_float4(v.x*INVLN2, v.y*INVLN2, v.z*INVLN2, v.w*INVLN2);
        }
        for (int i = tid; i < 1024; i += 256) {
            float4 v = t4[i];
            strv[i] = make_float4(v.x*INVLN2, v.y*INVLN2, v.z*INVLN2, v.w*INVLN2);
        }
    }
    __syncthreads();

    const int wid  = tid >> 6;
    const int lane = tid & 63;
    const int b    = lane & 15;
    const int L    = len_g[beta];

    if (wid == 0) {
        // ---------------- forward ----------------
        float* Ub = Ubuf + (size_t)beta * (T * NB);
        float* Vb = Vbuf + (size_t)beta * ((T + 1) * NB);
        float PA = 0.f, Q = 0.f;
        float R = strt[b] - AP2;               // U[b,0]
        if (lane < 16) Ub[b] = R;
        float TL = 0.f;

        float  ca  = act[b];                                   // row 0
        float2 cs  = *(const float2*)(stp + b * 2);            // LDS row 0 = glob 1
        float  cst = strt[16 + b];                             // row 1

        for (int t = 1; t <= T; ++t) {
            // depth-1 prefetch (clamped; overflow rows unused)
            float  na  = act[(t & 255) * 16 + b];
            float2 ns  = *(const float2*)(stp + (t & 255) * 32 + b * 2);
            float  nst = strt[((t + 1) & 255) * 16 + b];

            PA += ca;
            float V = PA + Q + cs.x;
            float G = lse16_2(R + V);
            if (t == L) TL = G;
            Q += cs.y;
            if (lane < 16) Vb[t * 16 + b] = V;
            if (t < T) {
                float U = G + (cst - AP2) - PA - Q;
                if (lane < 16) Ub[t * 16 + b] = U;
                R = lse2_2(R, U);
            }
            ca = na; cs = ns; cst = nst;
        }
        if (lane == 0) TLbuf[beta] = TL;
    } else if (wid == 1) {
        // ---------------- backward ----------------
        float fn0 = NEGV, fn1 = 0.f;
        if (lane == 0) Wbuf[beta * (T + 1) + T] = 0.f;

        float  ca  = act[(T - 1) * 16 + b];
        float2 cs  = *(const float2*)(stp + (T - 1) * 32 + b * 2); // glob row T
        float  cst = strt[(T - 1) * 16 + b];

        for (int i = T - 1; i >= 0; --i) {
            const int pr = (i - 1) & 255;       // i=0 -> 255, unused
            float  na  = act[pr * 16 + b];
            float2 ns  = *(const float2*)(stp + pr * 32 + b * 2);
            float  nst = strt[pr * 16 + b];

            float t0  = cs.y + fn0;             // rev e0 = orig e1
            float t1  = cs.x + fn1;             // rev e1 = orig e0
            float f0c = ca + lse2_2(t0, t1);
            float f1c = lse16_2((cst - AP2) + f0c);
            const bool mk = (i < L);
            fn0 = mk ? f0c : NEGV;
            fn1 = mk ? f1c : 0.f;
            if (i >= 1 && lane == 0) Wbuf[beta * (T + 1) + i] = fn1;
            ca = na; cs = ns; cst = nst;
        }
    }
}

// One block per (beta, t). Partial sums to unique scratch slots (no atomics).
__global__ __launch_bounds__(256) void cc_kernel(
    const float* __restrict__ pens,   // [B][257][257][16]
    const int*   __restrict__ len_g,
    const float* __restrict__ Wbuf,
    const float* __restrict__ TLbuf,
    const float* __restrict__ Ubuf,
    const float* __restrict__ Vbuf,
    float* __restrict__ part)         // [T*B]
{
    const int beta = blockIdx.x;
    const int t    = blockIdx.y + 1;
    const int tid  = threadIdx.x;
    const int pidx = blockIdx.y * B + beta;
    const int L    = len_g[beta];
    if (t > L) { if (tid == 0) part[pidx] = 0.f; return; }

    const float c0 = Wbuf[beta * (T + 1) + t] - TLbuf[beta];   // log2
    const float4* U4 = (const float4*)(Ubuf + (size_t)beta * (T * NB));
    const float4* P4 = (const float4*)(pens + (size_t)beta * ((size_t)(T+1)*(T+1)*NB)
                                            + (size_t)t * NB);
    const int q = tid & 3;                     // constant per thread (stride 256 ≡ 0 mod 4)
    float4 vq = ((const float4*)(Vbuf + (size_t)beta * ((T + 1) * NB) + t * NB))[q];
    vq.x += c0; vq.y += c0; vq.z += c0; vq.w += c0;

    float local = 0.f;
    const int n4 = t * 4;                      // t rows x 4 float4
    for (int i4 = tid; i4 < n4; i4 += 256) {
        const int tau = i4 >> 2;
        float4 u = U4[i4];
        float4 p = P4[(size_t)tau * ((T + 1) * 4) + (i4 & 3)];
        local += fexp2(u.x + vq.x) * p.x + fexp2(u.y + vq.y) * p.y
               + fexp2(u.z + vq.z) * p.z + fexp2(u.w + vq.w) * p.w;
    }
#pragma unroll
    for (int off = 1; off < 64; off <<= 1) local += __shfl_xor(local, off);
    __shared__ float red[4];
    if ((tid & 63) == 0) red[tid >> 6] = local;
    __syncthreads();
    if (tid == 0) part[pidx] = red[0] + red[1] + red[2] + red[3];
}

// Reduce 8192 partials -> out[1]; reduce 32 TL -> out[0]. No atomics/memset.
__global__ __launch_bounds__(256) void final_kernel(
    const float* __restrict__ part, const float* __restrict__ TLbuf,
    float* __restrict__ out)
{
    const int tid = threadIdx.x;
    const float4* p4 = (const float4*)part;    // 2048 float4
    float s = 0.f;
#pragma unroll
    for (int k = 0; k < 8; ++k) {
        float4 v = p4[tid + 256 * k];
        s += v.x + v.y + v.z + v.w;
    }
#pragma unroll
    for (int off = 1; off < 64; off <<= 1) s += __shfl_xor(s, off);
    __shared__ float red[4];
    if ((tid & 63) == 0) red[tid >> 6] = s;
    __syncthreads();
    if (tid == 0) out[1] = red[0] + red[1] + red[2] + red[3];

    float tl = (tid < 32) ? TLbuf[tid] : 0.f;
    if (tid < 64) {
#pragma unroll
        for (int off = 1; off < 32; off <<= 1) tl += __shfl_xor(tl, off);
        if (tid == 0) out[0] = tl * LN2;
    }
}

extern "C" void kernel_launch(void* const* d_in, const int* in_sizes, int n_in,
                              void* d_out, int out_size, void* d_ws, size_t ws_size,
                              hipStream_t stream) {
    (void)in_sizes; (void)n_in; (void)out_size; (void)ws_size;
    const float* act  = (const float*)d_in[0];
    const float* stp  = (const float*)d_in[1];
    const float* strt = (const float*)d_in[2];
    const float* pens = (const float*)d_in[3];
    const int*   lens = (const int*)d_in[5];
    float* out = (float*)d_out;

    float* ws    = (float*)d_ws;
    float* Wbuf  = ws;                            // 8224
    float* TLbuf = Wbuf + B * (T + 1);            // 32
    float* Ubuf  = TLbuf + B;                     // 131072 (16B-aligned)
    float* Vbuf  = Ubuf + (size_t)B * T * NB;     // 131584
    float* part  = Vbuf + (size_t)B * (T+1) * NB; // 8192

    scan_kernel<<<B, 256, 0, stream>>>(act, stp, strt, lens, Wbuf, TLbuf, Ubuf, Vbuf);
    cc_kernel<<<dim3(B, T), 256, 0, stream>>>(pens, lens, Wbuf, TLbuf, Ubuf, Vbuf, part);
    final_kernel<<<1, 256, 0, stream>>>(part, TLbuf, out);
}